// Round 12
// baseline (214.684 us; speedup 1.0000x reference)
//
#include <hip/hip_runtime.h>
#include <hip/hip_bf16.h>

#define B_    4
#define C_    256
#define NTOK  2304
#define NH    8
#define DH    32

typedef short bf16x8 __attribute__((ext_vector_type(8)));
typedef short bf16x4 __attribute__((ext_vector_type(4)));
typedef float f32x4  __attribute__((ext_vector_type(4)));

// f32 -> bf16 RNE.  gfx950 has V_CVT_PK_BF16_F32; fall back to manual RNE.
#if __has_builtin(__builtin_amdgcn_cvt_pk_bf16_f32)
__device__ __forceinline__ unsigned pack2_bf16(float a, float b) {
    auto v = __builtin_amdgcn_cvt_pk_bf16_f32(a, b);   // lo=cvt(a), hi=cvt(b)
    return __builtin_bit_cast(unsigned, v);
}
__device__ __forceinline__ short rne_bf16(float f) {
    auto v = __builtin_amdgcn_cvt_pk_bf16_f32(f, f);
    return (short)(__builtin_bit_cast(unsigned, v) & 0xffffu);
}
#else
__device__ __forceinline__ short rne_bf16(float f) {
    union { float f; unsigned u; } v; v.f = f;
    const unsigned r = v.u + 0x7fffu + ((v.u >> 16) & 1u);
    return (short)(r >> 16);
}
__device__ __forceinline__ unsigned pack2_bf16(float a, float b) {
    return (unsigned)(unsigned short)rne_bf16(a) | ((unsigned)(unsigned short)rne_bf16(b) << 16);
}
#endif
__device__ __forceinline__ float fast_exp2(float x) {
#if __has_builtin(__builtin_amdgcn_exp2f)
    return __builtin_amdgcn_exp2f(x);
#else
    return exp2f(x);
#endif
}

// ---------------------------------------------------------------------------
// Kernel 0: weights prep.  w_qkv (196608) + w_proj (65536) fp32 -> bf16.
// ---------------------------------------------------------------------------
__global__ __launch_bounds__(256) void prep_kernel(
    const float* __restrict__ wq, const float* __restrict__ wp,
    short* __restrict__ wqb, short* __restrict__ wpb)
{
    const int id = blockIdx.x * 256 + threadIdx.x;
    const int base = id * 16;
    #pragma unroll
    for (int u = 0; u < 4; ++u) {
        const int off = base + u * 4;
        float4 v; short* d;
        if (off < 196608) { v = *(const float4*)(wq + off); d = wqb + off; }
        else { v = *(const float4*)(wp + (off - 196608)); d = wpb + (off - 196608); }
        *(unsigned*)d       = pack2_bf16(v.x, v.y);
        *(unsigned*)(d + 2) = pack2_bf16(v.z, v.w);
    }
}

// ---------------------------------------------------------------------------
// Kernel 1: QKV projection, MFMA, fused x transpose+convert (r9 structure:
// 864 blocks, block = (b, 32-token m-tile, jg), 4 waves x 64-col j-tiles).
// q pre-scaled by dh^-0.5*log2(e); q,k -> [B*h,N,dh]; v -> [B*h,dh,N].
// ---------------------------------------------------------------------------
__global__ __launch_bounds__(256) void qkv_mfma(
    const float* __restrict__ x,    // [B][C][N] fp32
    const short* __restrict__ wqb,  // [768][256] bf16
    const float* __restrict__ bias, // [768] fp32
    short* __restrict__ qb, short* __restrict__ kb, short* __restrict__ vt)
{
    __shared__ short As[32][264];   // A tile [n][c], stride 264 (16B-mult)
    __shared__ short Es[4][2560];   // per-wave epilogue buffer
    const int t    = threadIdx.x;
    const int wave = t >> 6;
    const int lane = t & 63;
    const int quad = lane >> 4, l16 = lane & 15;
    const int blk  = blockIdx.x;          // 0..863
    const int b    = blk / 216;
    const int rem  = blk % 216;
    const int mt   = rem / 3;
    const int jg   = rem % 3;
    const int m0   = mt * 32;
    const int j0   = (jg * 4 + wave) * 64;

    // ---- stage A: x[b][c][m0..m0+32] -> As[n][c] bf16 (pairs of c rows)
    {
        const int n4  = (t & 7) * 4;
        const int tc2 = t >> 3;             // 0..31
        const float* xb = x + ((size_t)b * C_) * NTOK + m0 + n4;
        #pragma unroll
        for (int r = 0; r < 4; ++r) {
            const int c = tc2 * 2 + r * 64;
            const float4 v0 = *(const float4*)(xb + (size_t)c * NTOK);
            const float4 v1 = *(const float4*)(xb + (size_t)(c + 1) * NTOK);
            *(unsigned*)&As[n4 + 0][c] = pack2_bf16(v0.x, v1.x);
            *(unsigned*)&As[n4 + 1][c] = pack2_bf16(v0.y, v1.y);
            *(unsigned*)&As[n4 + 2][c] = pack2_bf16(v0.z, v1.z);
            *(unsigned*)&As[n4 + 3][c] = pack2_bf16(v0.w, v1.w);
        }
    }
    __syncthreads();

    const short* bbase = wqb + (size_t)(j0 + l16) * C_ + quad * 8;

    f32x4 acc[2][4] = {};
    for (int k0 = 0; k0 < C_; k0 += 32) {
        bf16x8 af[2], bfr[4];
        #pragma unroll
        for (int i = 0; i < 2; ++i)
            af[i] = *(const bf16x8*)&As[i * 16 + l16][k0 + quad * 8];
        #pragma unroll
        for (int j = 0; j < 4; ++j)
            bfr[j] = *(const bf16x8*)(bbase + (size_t)j * 16 * C_ + k0);
        #pragma unroll
        for (int i = 0; i < 2; ++i)
            #pragma unroll
            for (int j = 0; j < 4; ++j)
                acc[i][j] = __builtin_amdgcn_mfma_f32_16x16x32_bf16(af[i], bfr[j], acc[i][j], 0, 0, 0);
    }

    short* Ew = Es[wave];
    const int three = j0 >> 8;                 // wave-uniform: 0=q 1=k 2=v
    if (three < 2) {
        // Es layout [n(32)][j(64), stride 72]: scalar writes, b128 row reads
        const float sc = (three == 0) ? 0.25503486f : 1.0f;  // q: 32^-.5*log2e
        #pragma unroll
        for (int j = 0; j < 4; ++j) {
            const float bv = bias[j0 + j * 16 + l16];
            #pragma unroll
            for (int i = 0; i < 2; ++i)
                #pragma unroll
                for (int r = 0; r < 4; ++r) {
                    const int n_l = i * 16 + quad * 4 + r;
                    Ew[n_l * 72 + j * 16 + l16] = rne_bf16((acc[i][j][r] + bv) * sc);
                }
        }
        // wave-private LDS, no barrier
        const int n_l = lane & 31, hh = lane >> 5;
        const int head = ((j0 + hh * 32) >> 5) & 7;
        short* dst = ((three == 0) ? qb : kb)
                   + ((size_t)(b * NH + head) * NTOK + m0 + n_l) * DH;
        #pragma unroll
        for (int s = 0; s < 4; ++s)
            *(bf16x8*)(dst + s * 8) = *(const bf16x8*)&Ew[n_l * 72 + hh * 32 + s * 8];
    } else {
        // Es layout [j(64)][n(32), stride 40]: packed b32 writes, b128 reads
        #pragma unroll
        for (int j = 0; j < 4; ++j) {
            const float bv = bias[j0 + j * 16 + l16];
            const int j_l = j * 16 + l16;
            #pragma unroll
            for (int i = 0; i < 2; ++i) {
                const int nb = i * 16 + quad * 4;
                *(unsigned*)&Ew[j_l * 40 + nb] =
                    pack2_bf16(acc[i][j][0] + bv, acc[i][j][1] + bv);
                *(unsigned*)&Ew[j_l * 40 + nb + 2] =
                    pack2_bf16(acc[i][j][2] + bv, acc[i][j][3] + bv);
            }
        }
        #pragma unroll
        for (int p = 0; p < 4; ++p) {
            const int j_r = p * 16 + (lane >> 2);
            const int seg = (lane & 3) * 8;
            const int head = ((j0 + j_r) >> 5) & 7;
            const int d    = j_r & 31;
            *(bf16x8*)(vt + ((size_t)(b * NH + head) * DH + d) * NTOK + m0 + seg) =
                *(const bf16x8*)&Ew[j_r * 40 + seg];
        }
    }
}

// ---------------------------------------------------------------------------
// Kernel 2: BARRIER-FREE MFMA flash attention, split-K (max-free exp2
// softmax).  grid (36, 32, 2), block 256 (4 waves x 16 q-rows).
// K and V^T MFMA fragments are loaded DIRECTLY from global (L2-resident;
// K-fragment = 1KB contiguous per instruction) — no K/V LDS staging, no
// __syncthreads anywhere.  Only wave-private Ps LDS (8.7 KB) for the
// C-layout -> A-layout transpose of P.  Writes unnormalized O + l partials.
// ---------------------------------------------------------------------------
__global__ __launch_bounds__(256) void attn_kernel(
    const short* __restrict__ qg,
    const short* __restrict__ kg,
    const short* __restrict__ vg,
    float* __restrict__ po,      // [2][B*h][N][dh] fp32 unnormalized
    float* __restrict__ pl)      // [2][B*h][N] fp32 row sums
{
    const int bh   = blockIdx.y;
    const int q0   = blockIdx.x * 64;
    const int half = blockIdx.z;
    const int t    = threadIdx.x;
    const int wave = t >> 6;
    const int lane = t & 63;
    const int quad = lane >> 4;
    const int l16  = lane & 15;

    __shared__ short Ps[4][16][68];   // per-wave P [i][j] (wave-private)

    const short* kbase = kg + (size_t)bh * NTOK * DH;
    const short* vbase = vg + (size_t)bh * DH * NTOK;

    const short* qptr = qg + ((size_t)bh * NTOK + q0 + wave * 16 + l16) * DH + quad * 8;
    const bf16x8 qf = *(const bf16x8*)qptr;

    // per-lane K/V fragment base pointers (advance by 64 keys per iter)
    const short* kfp = kbase + (size_t)(half * (NTOK / 2) + l16) * DH + quad * 8;
    const short* vfp0 = vbase + (size_t)l16 * NTOK + half * (NTOK / 2) + quad * 8;
    const short* vfp1 = vfp0 + (size_t)16 * NTOK;

    f32x4 Oc0 = {0.f, 0.f, 0.f, 0.f};
    f32x4 Oc1 = {0.f, 0.f, 0.f, 0.f};
    float lpart[4] = {0.f, 0.f, 0.f, 0.f};

    for (int it = 0; it < (NTOK / 2) / 64; ++it) {
        // QK^T: S[jt][r] -> score(row=quad*4+r, col=jt*16+l16)
        bf16x8 kf[4];
        #pragma unroll
        for (int jt = 0; jt < 4; ++jt)
            kf[jt] = *(const bf16x8*)(kfp + (size_t)(it * 64 + jt * 16) * DH);
        f32x4 S[4];
        #pragma unroll
        for (int jt = 0; jt < 4; ++jt) {
            f32x4 z = {0.f, 0.f, 0.f, 0.f};
            S[jt] = __builtin_amdgcn_mfma_f32_16x16x32_bf16(qf, kf[jt], z, 0, 0, 0);
        }

        // p = 2^s (log2e folded into q), park in wave-private LDS A-layout
        #pragma unroll
        for (int jt = 0; jt < 4; ++jt) {
            #pragma unroll
            for (int r = 0; r < 4; ++r) {
                const float p = fast_exp2(S[jt][r]);
                lpart[r] += p;
                Ps[wave][quad * 4 + r][jt * 16 + l16] = rne_bf16(p);
            }
        }

        // PV: O[row][d] += P[row][j] * V[j][d]; V^T fragments from global
        #pragma unroll
        for (int jc = 0; jc < 2; ++jc) {
            const bf16x4 p0 = *(const bf16x4*)&Ps[wave][l16][jc * 32 + quad * 8];
            const bf16x4 p1 = *(const bf16x4*)&Ps[wave][l16][jc * 32 + quad * 8 + 4];
            bf16x8 af;
            af[0] = p0[0]; af[1] = p0[1]; af[2] = p0[2]; af[3] = p0[3];
            af[4] = p1[0]; af[5] = p1[1]; af[6] = p1[2]; af[7] = p1[3];
            const bf16x8 b0 = *(const bf16x8*)(vfp0 + it * 64 + jc * 32);
            const bf16x8 b1 = *(const bf16x8*)(vfp1 + it * 64 + jc * 32);
            Oc0 = __builtin_amdgcn_mfma_f32_16x16x32_bf16(af, b0, Oc0, 0, 0, 0);
            Oc1 = __builtin_amdgcn_mfma_f32_16x16x32_bf16(af, b1, Oc1, 0, 0, 0);
        }
    }

    // row-sum l across the 16-lane column groups
    #pragma unroll
    for (int off = 1; off < 16; off <<= 1) {
        #pragma unroll
        for (int r = 0; r < 4; ++r)
            lpart[r] += __shfl_xor(lpart[r], off, 64);
    }

    const size_t rowbase = ((size_t)half * 32 + bh) * NTOK + q0 + wave * 16 + quad * 4;
    float* obase = po + rowbase * DH + l16;
    #pragma unroll
    for (int r = 0; r < 4; ++r) {
        obase[(size_t)r * DH]      = Oc0[r];
        obase[(size_t)r * DH + 16] = Oc1[r];
    }
    if (l16 == 0) {
        float* lb = pl + rowbase;
        #pragma unroll
        for (int r = 0; r < 4; ++r) lb[r] = lpart[r];
    }
}

// ---------------------------------------------------------------------------
// Kernel 3: output projection, MFMA, split-K combine staged ONCE per block
// (r9 structure: 288 blocks, 32-token m-tiles).
// ---------------------------------------------------------------------------
__global__ __launch_bounds__(256) void proj_mfma(
    const float* __restrict__ po,   // [2][B*h][N][dh] fp32
    const float* __restrict__ pl,   // [2][B*h][N] fp32
    const short* __restrict__ wpb,  // [256][256] bf16
    const float* __restrict__ bias, // [256] fp32
    float* __restrict__ out)        // [B][256][2304] fp32
{
    __shared__ short Ac[32 * 336];  // combined A tile [m][head*40 + d]
    __shared__ float Ep[4][2304];   // per-wave epilogue [c(64)][stride 36]
    const int t    = threadIdx.x;
    const int wave = t >> 6;
    const int lane = t & 63;
    const int quad = lane >> 4, l16 = lane & 15;
    const int blk  = blockIdx.x;          // 0..287
    const int b    = blk / 72;
    const int mt   = blk % 72;
    const int m0   = mt * 32;
    const int c0   = wave * 64;

    const size_t PO_OFF = (size_t)32 * NTOK * DH;
    const size_t PL_OFF = (size_t)32 * NTOK;

    // ---- stage combined A: thread t covers (m = t>>3, d = (t&7)*4) per head
    {
        const int m  = t >> 3;
        const int d4 = (t & 7) * 4;
        #pragma unroll
        for (int h = 0; h < NH; ++h) {
            const size_t row  = (size_t)(b * NH + h) * NTOK + m0 + m;
            const float inv = 1.f / (pl[row] + pl[PL_OFF + row]);
            const float* p0 = po + row * DH + d4;
            const f32x4 a = *(const f32x4*)p0;
            const f32x4 c = *(const f32x4*)(p0 + PO_OFF);
            short* dst = &Ac[m * 336 + h * 40 + d4];
            *(unsigned*)dst       = pack2_bf16((a[0] + c[0]) * inv, (a[1] + c[1]) * inv);
            *(unsigned*)(dst + 2) = pack2_bf16((a[2] + c[2]) * inv, (a[3] + c[3]) * inv);
        }
    }
    __syncthreads();

    const short* bbase = wpb + (size_t)(c0 + l16) * C_ + quad * 8;

    f32x4 acc[2][4] = {};
    for (int kt = 0; kt < 8; ++kt) {            // head = kt
        bf16x8 af[2], bfr[4];
        #pragma unroll
        for (int i = 0; i < 2; ++i)
            af[i] = *(const bf16x8*)&Ac[(i * 16 + l16) * 336 + kt * 40 + quad * 8];
        #pragma unroll
        for (int j = 0; j < 4; ++j)
            bfr[j] = *(const bf16x8*)(bbase + (size_t)j * 16 * C_ + kt * 32);
        #pragma unroll
        for (int i = 0; i < 2; ++i)
            #pragma unroll
            for (int j = 0; j < 4; ++j)
                acc[i][j] = __builtin_amdgcn_mfma_f32_16x16x32_bf16(af[i], bfr[j], acc[i][j], 0, 0, 0);
    }

    float* Ew = Ep[wave];
    #pragma unroll
    for (int j = 0; j < 4; ++j) {
        const int j_l = j * 16 + l16;
        const float bv = bias[c0 + j_l];
        #pragma unroll
        for (int i = 0; i < 2; ++i) {
            f32x4 st = {acc[i][j][0] + bv, acc[i][j][1] + bv,
                        acc[i][j][2] + bv, acc[i][j][3] + bv};
            *(f32x4*)&Ew[j_l * 36 + i * 16 + quad * 4] = st;
        }
    }
    #pragma unroll
    for (int p = 0; p < 8; ++p) {
        const int c_r = p * 8 + (lane >> 3);
        const int seg = (lane & 7) * 4;
        *(float4*)(out + ((size_t)b * C_ + c0 + c_r) * NTOK + m0 + seg) =
            *(const float4*)&Ew[c_r * 36 + seg];
    }
}

// ---------------------------------------------------------------------------
extern "C" void kernel_launch(void* const* d_in, const int* in_sizes, int n_in,
                              void* d_out, int out_size, void* d_ws, size_t ws_size,
                              hipStream_t stream) {
    const float* x      = (const float*)d_in[0];
    const float* w_qkv  = (const float*)d_in[1];
    const float* b_qkv  = (const float*)d_in[2];
    const float* w_proj = (const float*)d_in[3];
    const float* b_proj = (const float*)d_in[4];
    float* out = (float*)d_out;

    const size_t SZ = (size_t)B_ * NH * NTOK * DH;   // 2359296
    short* wqb = (short*)d_ws;            // [768][256]
    short* wpb = wqb + 196608;            // [256][256]
    short* qb  = wpb + 65536;
    short* kb  = qb + SZ;
    short* vt  = kb + SZ;
    float* po  = (float*)(vt + SZ);       // [2][32][2304][32] fp32 (16B-aligned)
    float* pl  = po + 2 * SZ;             // [2][32][2304] fp32

    prep_kernel<<<64, 256, 0, stream>>>(w_qkv, w_proj, wqb, wpb);
    qkv_mfma<<<864, 256, 0, stream>>>(x, wqb, b_qkv, qb, kb, vt);
    attn_kernel<<<dim3(36, 32, 2), 256, 0, stream>>>(qb, kb, vt, po, pl);
    proj_mfma<<<288, 256, 0, stream>>>(po, pl, wpb, b_proj, out);
}

// Round 13
// 152.587 us; speedup vs baseline: 1.4070x; 1.4070x over previous
//
#include <hip/hip_runtime.h>
#include <hip/hip_bf16.h>

#define B_    4
#define C_    256
#define NTOK  2304
#define NH    8
#define DH    32

typedef short bf16x8 __attribute__((ext_vector_type(8)));
typedef short bf16x4 __attribute__((ext_vector_type(4)));
typedef float f32x4  __attribute__((ext_vector_type(4)));

// f32 -> bf16 RNE.  gfx950 has V_CVT_PK_BF16_F32; fall back to manual RNE.
#if __has_builtin(__builtin_amdgcn_cvt_pk_bf16_f32)
__device__ __forceinline__ unsigned pack2_bf16(float a, float b) {
    auto v = __builtin_amdgcn_cvt_pk_bf16_f32(a, b);   // lo=cvt(a), hi=cvt(b)
    return __builtin_bit_cast(unsigned, v);
}
__device__ __forceinline__ short rne_bf16(float f) {
    auto v = __builtin_amdgcn_cvt_pk_bf16_f32(f, f);
    return (short)(__builtin_bit_cast(unsigned, v) & 0xffffu);
}
#else
__device__ __forceinline__ short rne_bf16(float f) {
    union { float f; unsigned u; } v; v.f = f;
    const unsigned r = v.u + 0x7fffu + ((v.u >> 16) & 1u);
    return (short)(r >> 16);
}
__device__ __forceinline__ unsigned pack2_bf16(float a, float b) {
    return (unsigned)(unsigned short)rne_bf16(a) | ((unsigned)(unsigned short)rne_bf16(b) << 16);
}
#endif
__device__ __forceinline__ float fast_exp2(float x) {
#if __has_builtin(__builtin_amdgcn_exp2f)
    return __builtin_amdgcn_exp2f(x);
#else
    return exp2f(x);
#endif
}

// ---------------------------------------------------------------------------
// Kernel 0: weights prep.  w_qkv (196608) + w_proj (65536) fp32 -> bf16.
// ---------------------------------------------------------------------------
__global__ __launch_bounds__(256) void prep_kernel(
    const float* __restrict__ wq, const float* __restrict__ wp,
    short* __restrict__ wqb, short* __restrict__ wpb)
{
    const int id = blockIdx.x * 256 + threadIdx.x;
    const int base = id * 16;
    #pragma unroll
    for (int u = 0; u < 4; ++u) {
        const int off = base + u * 4;
        float4 v; short* d;
        if (off < 196608) { v = *(const float4*)(wq + off); d = wqb + off; }
        else { v = *(const float4*)(wp + (off - 196608)); d = wpb + (off - 196608); }
        *(unsigned*)d       = pack2_bf16(v.x, v.y);
        *(unsigned*)(d + 2) = pack2_bf16(v.z, v.w);
    }
}

// ---------------------------------------------------------------------------
// Kernel 1: QKV projection, MFMA, fused x transpose+convert (r9 structure:
// 864 blocks, block = (b, 32-token m-tile, jg), 4 waves x 64-col j-tiles).
// q pre-scaled by dh^-0.5*log2(e); q,k -> [B*h,N,dh]; v -> [B*h,dh,N].
// ---------------------------------------------------------------------------
__global__ __launch_bounds__(256) void qkv_mfma(
    const float* __restrict__ x,    // [B][C][N] fp32
    const short* __restrict__ wqb,  // [768][256] bf16
    const float* __restrict__ bias, // [768] fp32
    short* __restrict__ qb, short* __restrict__ kb, short* __restrict__ vt)
{
    __shared__ short As[32][264];   // A tile [n][c], stride 264 (16B-mult)
    __shared__ short Es[4][2560];   // per-wave epilogue buffer
    const int t    = threadIdx.x;
    const int wave = t >> 6;
    const int lane = t & 63;
    const int quad = lane >> 4, l16 = lane & 15;
    const int blk  = blockIdx.x;          // 0..863
    const int b    = blk / 216;
    const int rem  = blk % 216;
    const int mt   = rem / 3;
    const int jg   = rem % 3;
    const int m0   = mt * 32;
    const int j0   = (jg * 4 + wave) * 64;

    // ---- stage A: x[b][c][m0..m0+32] -> As[n][c] bf16 (pairs of c rows)
    {
        const int n4  = (t & 7) * 4;
        const int tc2 = t >> 3;             // 0..31
        const float* xb = x + ((size_t)b * C_) * NTOK + m0 + n4;
        #pragma unroll
        for (int r = 0; r < 4; ++r) {
            const int c = tc2 * 2 + r * 64;
            const float4 v0 = *(const float4*)(xb + (size_t)c * NTOK);
            const float4 v1 = *(const float4*)(xb + (size_t)(c + 1) * NTOK);
            *(unsigned*)&As[n4 + 0][c] = pack2_bf16(v0.x, v1.x);
            *(unsigned*)&As[n4 + 1][c] = pack2_bf16(v0.y, v1.y);
            *(unsigned*)&As[n4 + 2][c] = pack2_bf16(v0.z, v1.z);
            *(unsigned*)&As[n4 + 3][c] = pack2_bf16(v0.w, v1.w);
        }
    }
    __syncthreads();

    const short* bbase = wqb + (size_t)(j0 + l16) * C_ + quad * 8;

    f32x4 acc[2][4] = {};
    for (int k0 = 0; k0 < C_; k0 += 32) {
        bf16x8 af[2], bfr[4];
        #pragma unroll
        for (int i = 0; i < 2; ++i)
            af[i] = *(const bf16x8*)&As[i * 16 + l16][k0 + quad * 8];
        #pragma unroll
        for (int j = 0; j < 4; ++j)
            bfr[j] = *(const bf16x8*)(bbase + (size_t)j * 16 * C_ + k0);
        #pragma unroll
        for (int i = 0; i < 2; ++i)
            #pragma unroll
            for (int j = 0; j < 4; ++j)
                acc[i][j] = __builtin_amdgcn_mfma_f32_16x16x32_bf16(af[i], bfr[j], acc[i][j], 0, 0, 0);
    }

    short* Ew = Es[wave];
    const int three = j0 >> 8;                 // wave-uniform: 0=q 1=k 2=v
    if (three < 2) {
        // Es layout [n(32)][j(64), stride 72]: scalar writes, b128 row reads
        const float sc = (three == 0) ? 0.25503486f : 1.0f;  // q: 32^-.5*log2e
        #pragma unroll
        for (int j = 0; j < 4; ++j) {
            const float bv = bias[j0 + j * 16 + l16];
            #pragma unroll
            for (int i = 0; i < 2; ++i)
                #pragma unroll
                for (int r = 0; r < 4; ++r) {
                    const int n_l = i * 16 + quad * 4 + r;
                    Ew[n_l * 72 + j * 16 + l16] = rne_bf16((acc[i][j][r] + bv) * sc);
                }
        }
        // wave-private LDS, no barrier
        const int n_l = lane & 31, hh = lane >> 5;
        const int head = ((j0 + hh * 32) >> 5) & 7;
        short* dst = ((three == 0) ? qb : kb)
                   + ((size_t)(b * NH + head) * NTOK + m0 + n_l) * DH;
        #pragma unroll
        for (int s = 0; s < 4; ++s)
            *(bf16x8*)(dst + s * 8) = *(const bf16x8*)&Ew[n_l * 72 + hh * 32 + s * 8];
    } else {
        // Es layout [j(64)][n(32), stride 40]: packed b32 writes, b128 reads
        #pragma unroll
        for (int j = 0; j < 4; ++j) {
            const float bv = bias[j0 + j * 16 + l16];
            const int j_l = j * 16 + l16;
            #pragma unroll
            for (int i = 0; i < 2; ++i) {
                const int nb = i * 16 + quad * 4;
                *(unsigned*)&Ew[j_l * 40 + nb] =
                    pack2_bf16(acc[i][j][0] + bv, acc[i][j][1] + bv);
                *(unsigned*)&Ew[j_l * 40 + nb + 2] =
                    pack2_bf16(acc[i][j][2] + bv, acc[i][j][3] + bv);
            }
        }
        #pragma unroll
        for (int p = 0; p < 4; ++p) {
            const int j_r = p * 16 + (lane >> 2);
            const int seg = (lane & 3) * 8;
            const int head = ((j0 + j_r) >> 5) & 7;
            const int d    = j_r & 31;
            *(bf16x8*)(vt + ((size_t)(b * NH + head) * DH + d) * NTOK + m0 + seg) =
                *(const bf16x8*)&Ew[j_r * 40 + seg];
        }
    }
}

// ---------------------------------------------------------------------------
// Kernel 2: MFMA flash attention, split-K, max-free exp2 softmax, register-
// prefetched LDS staging (r9 structure) with the S^T OPERAND-SWAP layout:
// QK is computed as mfma(A=K-frag, B=Q-frag) so each lane's 4 C-registers
// hold 4 CONSECUTIVE KEYS of one query -> P parks as packed b32 pairs
// (8 cvt_pk + 8 ds_write_b32 per tile, vs 16 rne + 16 ds_write_b16) and the
// PV A-fragment is a single aligned ds_read_b128.  P/O values bitwise equal
// to r9; only l's summation order differs (+-1 ulp).
// grid (36, 32, 2), block 256 (4 waves x 16 q-rows).
// ---------------------------------------------------------------------------
__global__ __launch_bounds__(256) void attn_kernel(
    const short* __restrict__ qg,
    const short* __restrict__ kg,
    const short* __restrict__ vg,
    float* __restrict__ po,      // [2][B*h][N][dh] fp32 unnormalized
    float* __restrict__ pl)      // [2][B*h][N] fp32 row sums
{
    const int bh   = blockIdx.y;
    const int q0   = blockIdx.x * 64;
    const int half = blockIdx.z;
    const int t    = threadIdx.x;
    const int wave = t >> 6;
    const int lane = t & 63;
    const int quad = lane >> 4;
    const int l16  = lane & 15;

    __shared__ short Ks[64][40];      // K tile  [j][d]
    __shared__ short Vt[32][72];      // V^T tile [d][j]
    __shared__ short Ps[4][16][72];   // per-wave P [query][key], 16B rows

    const short* kbase = kg + (size_t)bh * NTOK * DH;
    const short* vbase = vg + (size_t)bh * DH * NTOK;

    const short* qptr = qg + ((size_t)bh * NTOK + q0 + wave * 16 + l16) * DH + quad * 8;
    const bf16x8 qf = *(const bf16x8*)qptr;

    f32x4 Oc0 = {0.f, 0.f, 0.f, 0.f};
    f32x4 Oc1 = {0.f, 0.f, 0.f, 0.f};
    float lsum = 0.f;

    const int kbeg = half * (NTOK / 2);
    const int kend = kbeg + (NTOK / 2);

    const int kr = t >> 2, ksg = t & 3;       // K staging: 16B/thread
    const int vr = t >> 3, vsg = t & 7;       // V^T staging: 16B/thread

    bf16x8 kreg = *(const bf16x8*)(kbase + (size_t)(kbeg + kr) * DH + ksg * 8);
    bf16x8 vreg = *(const bf16x8*)(vbase + (size_t)vr * NTOK + kbeg + vsg * 8);

    for (int kt = kbeg; kt < kend; kt += 64) {
        *(bf16x8*)&Ks[kr][ksg * 8] = kreg;
        *(bf16x8*)&Vt[vr][vsg * 8] = vreg;
        __syncthreads();

        const int ktn = (kt + 64 < kend) ? kt + 64 : kbeg;
        kreg = *(const bf16x8*)(kbase + (size_t)(ktn + kr) * DH + ksg * 8);
        vreg = *(const bf16x8*)(vbase + (size_t)vr * NTOK + ktn + vsg * 8);

        // S^T: mfma(A=kf, B=qf) -> lane holds S^T[key=jt*16+quad*4+r][query=l16]
        f32x4 S[4];
        #pragma unroll
        for (int jt = 0; jt < 4; ++jt) {
            const bf16x8 kf = *(const bf16x8*)&Ks[jt * 16 + l16][quad * 8];
            f32x4 z = {0.f, 0.f, 0.f, 0.f};
            S[jt] = __builtin_amdgcn_mfma_f32_16x16x32_bf16(kf, qf, z, 0, 0, 0);
        }

        // p = 2^s; park packed pairs into P[query][key] (wave-private LDS)
        #pragma unroll
        for (int jt = 0; jt < 4; ++jt) {
            const float p0 = fast_exp2(S[jt][0]);
            const float p1 = fast_exp2(S[jt][1]);
            const float p2 = fast_exp2(S[jt][2]);
            const float p3 = fast_exp2(S[jt][3]);
            lsum += (p0 + p1) + (p2 + p3);
            *(unsigned*)&Ps[wave][l16][jt * 16 + quad * 4]     = pack2_bf16(p0, p1);
            *(unsigned*)&Ps[wave][l16][jt * 16 + quad * 4 + 2] = pack2_bf16(p2, p3);
        }

        // PV: O[query][d] += P[query][key] * V[key][d]
        #pragma unroll
        for (int jc = 0; jc < 2; ++jc) {
            const bf16x8 af = *(const bf16x8*)&Ps[wave][l16][jc * 32 + quad * 8];
            const bf16x8 b0 = *(const bf16x8*)&Vt[l16][jc * 32 + quad * 8];
            const bf16x8 b1 = *(const bf16x8*)&Vt[16 + l16][jc * 32 + quad * 8];
            Oc0 = __builtin_amdgcn_mfma_f32_16x16x32_bf16(af, b0, Oc0, 0, 0, 0);
            Oc1 = __builtin_amdgcn_mfma_f32_16x16x32_bf16(af, b1, Oc1, 0, 0, 0);
        }
        __syncthreads();
    }

    // l for query l16: sum the 4 quad-partials
    lsum += __shfl_xor(lsum, 16, 64);
    lsum += __shfl_xor(lsum, 32, 64);

    const size_t rowbase = ((size_t)half * 32 + bh) * NTOK + q0 + wave * 16;
    float* obase = po + (rowbase + quad * 4) * DH + l16;
    #pragma unroll
    for (int r = 0; r < 4; ++r) {
        obase[(size_t)r * DH]      = Oc0[r];
        obase[(size_t)r * DH + 16] = Oc1[r];
    }
    if (quad == 0) pl[rowbase + l16] = lsum;
}

// ---------------------------------------------------------------------------
// Kernel 3: output projection, MFMA, split-K combine staged ONCE per block
// (r9 structure: 288 blocks, 32-token m-tiles).
// ---------------------------------------------------------------------------
__global__ __launch_bounds__(256) void proj_mfma(
    const float* __restrict__ po,   // [2][B*h][N][dh] fp32
    const float* __restrict__ pl,   // [2][B*h][N] fp32
    const short* __restrict__ wpb,  // [256][256] bf16
    const float* __restrict__ bias, // [256] fp32
    float* __restrict__ out)        // [B][256][2304] fp32
{
    __shared__ short Ac[32 * 336];  // combined A tile [m][head*40 + d]
    __shared__ float Ep[4][2304];   // per-wave epilogue [c(64)][stride 36]
    const int t    = threadIdx.x;
    const int wave = t >> 6;
    const int lane = t & 63;
    const int quad = lane >> 4, l16 = lane & 15;
    const int blk  = blockIdx.x;          // 0..287
    const int b    = blk / 72;
    const int mt   = blk % 72;
    const int m0   = mt * 32;
    const int c0   = wave * 64;

    const size_t PO_OFF = (size_t)32 * NTOK * DH;
    const size_t PL_OFF = (size_t)32 * NTOK;

    // ---- stage combined A: thread t covers (m = t>>3, d = (t&7)*4) per head
    {
        const int m  = t >> 3;
        const int d4 = (t & 7) * 4;
        #pragma unroll
        for (int h = 0; h < NH; ++h) {
            const size_t row  = (size_t)(b * NH + h) * NTOK + m0 + m;
            const float inv = 1.f / (pl[row] + pl[PL_OFF + row]);
            const float* p0 = po + row * DH + d4;
            const f32x4 a = *(const f32x4*)p0;
            const f32x4 c = *(const f32x4*)(p0 + PO_OFF);
            short* dst = &Ac[m * 336 + h * 40 + d4];
            *(unsigned*)dst       = pack2_bf16((a[0] + c[0]) * inv, (a[1] + c[1]) * inv);
            *(unsigned*)(dst + 2) = pack2_bf16((a[2] + c[2]) * inv, (a[3] + c[3]) * inv);
        }
    }
    __syncthreads();

    const short* bbase = wpb + (size_t)(c0 + l16) * C_ + quad * 8;

    f32x4 acc[2][4] = {};
    for (int kt = 0; kt < 8; ++kt) {            // head = kt
        bf16x8 af[2], bfr[4];
        #pragma unroll
        for (int i = 0; i < 2; ++i)
            af[i] = *(const bf16x8*)&Ac[(i * 16 + l16) * 336 + kt * 40 + quad * 8];
        #pragma unroll
        for (int j = 0; j < 4; ++j)
            bfr[j] = *(const bf16x8*)(bbase + (size_t)j * 16 * C_ + kt * 32);
        #pragma unroll
        for (int i = 0; i < 2; ++i)
            #pragma unroll
            for (int j = 0; j < 4; ++j)
                acc[i][j] = __builtin_amdgcn_mfma_f32_16x16x32_bf16(af[i], bfr[j], acc[i][j], 0, 0, 0);
    }

    float* Ew = Ep[wave];
    #pragma unroll
    for (int j = 0; j < 4; ++j) {
        const int j_l = j * 16 + l16;
        const float bv = bias[c0 + j_l];
        #pragma unroll
        for (int i = 0; i < 2; ++i) {
            f32x4 st = {acc[i][j][0] + bv, acc[i][j][1] + bv,
                        acc[i][j][2] + bv, acc[i][j][3] + bv};
            *(f32x4*)&Ew[j_l * 36 + i * 16 + quad * 4] = st;
        }
    }
    #pragma unroll
    for (int p = 0; p < 8; ++p) {
        const int c_r = p * 8 + (lane >> 3);
        const int seg = (lane & 7) * 4;
        *(float4*)(out + ((size_t)b * C_ + c0 + c_r) * NTOK + m0 + seg) =
            *(const float4*)&Ew[c_r * 36 + seg];
    }
}

// ---------------------------------------------------------------------------
extern "C" void kernel_launch(void* const* d_in, const int* in_sizes, int n_in,
                              void* d_out, int out_size, void* d_ws, size_t ws_size,
                              hipStream_t stream) {
    const float* x      = (const float*)d_in[0];
    const float* w_qkv  = (const float*)d_in[1];
    const float* b_qkv  = (const float*)d_in[2];
    const float* w_proj = (const float*)d_in[3];
    const float* b_proj = (const float*)d_in[4];
    float* out = (float*)d_out;

    const size_t SZ = (size_t)B_ * NH * NTOK * DH;   // 2359296
    short* wqb = (short*)d_ws;            // [768][256]
    short* wpb = wqb + 196608;            // [256][256]
    short* qb  = wpb + 65536;
    short* kb  = qb + SZ;
    short* vt  = kb + SZ;
    float* po  = (float*)(vt + SZ);       // [2][32][2304][32] fp32 (16B-aligned)
    float* pl  = po + 2 * SZ;             // [2][32][2304] fp32

    prep_kernel<<<64, 256, 0, stream>>>(w_qkv, w_proj, wqb, wpb);
    qkv_mfma<<<864, 256, 0, stream>>>(x, wqb, b_qkv, qb, kb, vt);
    attn_kernel<<<dim3(36, 32, 2), 256, 0, stream>>>(qb, kb, vt, po, pl);
    proj_mfma<<<288, 256, 0, stream>>>(po, pl, wpb, b_proj, out);
}